// Round 9
// baseline (232.419 us; speedup 1.0000x reference)
//
#include <hip/hip_runtime.h>

#define DEV __device__ __forceinline__

typedef __attribute__((ext_vector_type(8))) short short8;
typedef __attribute__((ext_vector_type(4))) float f32x4;
typedef __attribute__((ext_vector_type(2))) unsigned int u32x2;
typedef __attribute__((ext_vector_type(4))) unsigned int u32x4;

constexpr int Dm = 768;   // model dim
constexpr int Sn = 2048;  // seq len
constexpr int Bn = 4;     // batch
constexpr int Hn = 12;    // heads
constexpr int Mn = Bn * Sn;  // 8192 rows

// Q is pre-scaled by 0.125*log2(e) so scores come out as s*log2(e):
// p1 = exp2(sacc) = e^s ; p2 = relu(sacc)^2 = (log2e)^2 * relu(s)^2
constexpr float kQScale = 0.18033688011112043f;     // 0.125 * log2(e)
constexpr float kR2Fix  = 0.4804530139182014f;      // 1 / (log2(e))^2

DEV unsigned short f32_to_bf16(float f) {
  unsigned int u = __float_as_uint(f);
  u = (u + 0x7fffu + ((u >> 16) & 1u)) >> 16;
  return (unsigned short)u;
}

// gfx950: pack two fp32 -> bf16x2 dword in ONE VALU op (RNE).
DEV unsigned cvt_pk_bf16(float lo, float hi) {
  unsigned d;
  asm("v_cvt_pk_bf16_f32 %0, %1, %2" : "=v"(d) : "v"(lo), "v"(hi));
  return d;
}

DEV f32x4 mfma_bf16(short8 a, short8 b, f32x4 c) {
  return __builtin_amdgcn_mfma_f32_16x16x32_bf16(a, b, c, 0, 0, 0);
}

// async global->LDS, 16B per lane; LDS dest = wave-uniform base + lane*16
DEV void gload_lds16(const void* g, void* l) {
  __builtin_amdgcn_global_load_lds(
      (__attribute__((address_space(1))) const unsigned int*)g,
      (__attribute__((address_space(3))) unsigned int*)l, 16, 0, 0);
}

// pack 8 fp32 (two float4) -> 8 bf16 in one uint4 (RNE)
DEV uint4 pack8_bf16(float4 a, float4 b) {
  uint4 o;
  o.x = cvt_pk_bf16(a.x, a.y);
  o.y = cvt_pk_bf16(a.z, a.w);
  o.z = cvt_pk_bf16(b.x, b.y);
  o.w = cvt_pk_bf16(b.z, b.w);
  return o;
}

// Transform two 16x16 S^T C-layout tiles (packed as bf16 dwords) into one
// B-operand fragment for mfma_16x16x32 (K=32 keys spanning both tiles).
DEV short8 transpose_to_bfrag(unsigned xd0, unsigned xd1, unsigned yd0, unsigned yd1) {
  u32x2 a0 = __builtin_amdgcn_permlane32_swap(xd0, yd0, false, false);
  u32x2 b0 = __builtin_amdgcn_permlane16_swap(a0[0], a0[1], false, false);
  u32x2 a1 = __builtin_amdgcn_permlane32_swap(xd1, yd1, false, false);
  u32x2 b1 = __builtin_amdgcn_permlane16_swap(a1[0], a1[1], false, false);
  u32x4 f = {b0[0], b1[0], b0[1], b1[1]};
  return __builtin_bit_cast(short8, f);
}

// ---------------- weight cast kernel (weights only now) ----------------
// hs cast is fused into k_gemm_qkv's A staging (saves 24MB rd + 12MB wr +
// 12MB re-read of traffic and ~10us of kernel time).
__global__ __launch_bounds__(256) void k_cast_w(
    const float* __restrict__ Wq, const float* __restrict__ Wk,
    const float* __restrict__ Wv, const float* __restrict__ Wo,
    unsigned short* __restrict__ wbf) {
  int i = blockIdx.x * 256 + threadIdx.x;  // weights: 4*147456 float4
  int w = i / 147456;
  int off = i - w * 147456;
  const float* src = (w == 0) ? Wq : (w == 1) ? Wk : (w == 2) ? Wv : Wo;
  float4 v = ((const float4*)src)[off];
  ushort4 o;
  o.x = f32_to_bf16(v.x); o.y = f32_to_bf16(v.y);
  o.z = f32_to_bf16(v.z); o.w = f32_to_bf16(v.w);
  ((ushort4*)wbf)[w * 147456 + off] = o;
}

// ---------------- merged QKV projection GEMM ----------------
// Double-buffered LDS staging; unroll-2 kk loop; incremented pointers;
// XCD-chunked swizzle (768%8==0 bijective; each XCD gets 8 complete
// A-panels with all 12 N-readers co-located).
// NEW this round: A operand staged DIRECTLY from fp32 hidden_states via
// reg-staging (float4 loads -> cvt_pk_bf16 -> ds_write_b128), T14-style:
// loads issued in the prefetch slot, converts+writes after the MFMA
// cluster. Eliminates the separate hs-cast pass entirely.
__global__ __launch_bounds__(256, 3) void k_gemm_qkv(
    const float* __restrict__ hs, const unsigned short* __restrict__ wbf,
    const float* __restrict__ bq, const float* __restrict__ bk, const float* __restrict__ bv,
    unsigned short* __restrict__ Qb, unsigned short* __restrict__ Kb,
    unsigned short* __restrict__ Vt) {
  // union: 2 staging sets [As 128x32 | Bs 192x32] = 2*10240 shorts (40 KB)
  //        | V-transpose tile [96][136] = 13056 shorts (26 KB)
  __shared__ unsigned short Sh[2 * 10240];

  const int tid = threadIdx.x;
  const int wave = tid >> 6, lane = tid & 63;
  const int wm = wave >> 1, wn = wave & 1;
  const int quad = lane >> 4, l16 = lane & 15;
  // XCD-chunked swizzle: 768 blocks, 768%8==0 -> bijective.
  const int lin = blockIdx.x;
  const int swz = (lin & 7) * 96 + (lin >> 3);
  const int bxi = swz % 12;                   // N panel 0..11
  const int byi = swz / 12;                   // M panel 0..63
  const int bm = byi * 128, bn = bxi * 192;
  const int seg = bxi >> 2;                   // 0=Q 1=K 2=V
  const int nloc0 = (bxi & 3) * 192;          // column offset within 768

  const int sr = lane >> 2;
  const int sc = (lane & 3) * 8;
  // A source: fp32 hidden states (two float4 per lane per 16x32 block)
  const float* gAf0 = hs + (size_t)(bm + (wave * 2 + 0) * 16 + sr) * Dm + sc;
  const float* gAf1 = hs + (size_t)(bm + (wave * 2 + 1) * 16 + sr) * Dm + sc;
  const unsigned short* gB0 = wbf + (size_t)(bn + (wave * 3 + 0) * 16 + sr) * Dm + sc;
  const unsigned short* gB1 = wbf + (size_t)(bn + (wave * 3 + 1) * 16 + sr) * Dm + sc;
  const unsigned short* gB2 = wbf + (size_t)(bn + (wave * 3 + 2) * 16 + sr) * Dm + sc;
  // per-wave LDS staging offsets (within one set)
  const int oA0 = (wave * 2 + 0) * 512 + lane * 8;   // ds_write dest (shorts)
  const int oA1 = (wave * 2 + 1) * 512 + lane * 8;
  const int oB0 = 4096 + (wave * 3 + 0) * 512;
  const int oB1 = 4096 + (wave * 3 + 1) * 512;
  const int oB2 = 4096 + (wave * 3 + 2) * 512;

  f32x4 acc[4][6];
#pragma unroll
  for (int i = 0; i < 4; ++i)
#pragma unroll
    for (int j = 0; j < 6; ++j)
#pragma unroll
      for (int r = 0; r < 4; ++r) acc[i][j][r] = 0.f;

  // prologue: stage kk=0 into set 0
  {
    float4 a00 = *(const float4*)(gAf0);
    float4 a01 = *(const float4*)(gAf0 + 4);
    float4 a10 = *(const float4*)(gAf1);
    float4 a11 = *(const float4*)(gAf1 + 4);
    gload_lds16(gB0, &Sh[oB0]);
    gload_lds16(gB1, &Sh[oB1]);
    gload_lds16(gB2, &Sh[oB2]);
    *(uint4*)(&Sh[oA0]) = pack8_bf16(a00, a01);
    *(uint4*)(&Sh[oA1]) = pack8_bf16(a10, a11);
  }
  __syncthreads();  // set 0 ready

  // pointers to the NEXT k-step to stage
  const float* pAf0 = gAf0 + 32;
  const float* pAf1 = gAf1 + 32;
  const unsigned short* pB0 = gB0 + 32;
  const unsigned short* pB1 = gB1 + 32;
  const unsigned short* pB2 = gB2 + 32;

  constexpr int NK = Dm / 32;  // 24
#pragma unroll 2
  for (int kk = 0; kk < NK; ++kk) {
    const int cur = kk & 1;
    float4 a00, a01, a10, a11;
    unsigned short* nset = &Sh[(cur ^ 1) * 10240];
    const bool pf = (kk + 1 < NK);
    // issue loads early: A fp32 to regs, B async to LDS
    if (pf) {
      a00 = *(const float4*)(pAf0);
      a01 = *(const float4*)(pAf0 + 4);
      a10 = *(const float4*)(pAf1);
      a11 = *(const float4*)(pAf1 + 4);
      gload_lds16(pB0, nset + oB0);
      gload_lds16(pB1, nset + oB1);
      gload_lds16(pB2, nset + oB2);
      pAf0 += 32; pAf1 += 32; pB0 += 32; pB1 += 32; pB2 += 32;
    }

    const unsigned short* As = &Sh[cur * 10240];
    const unsigned short* Bs = As + 4096;
    short8 af[4], bf[6];
#pragma unroll
    for (int mi = 0; mi < 4; ++mi)
      af[mi] = *(const short8*)(&As[(wm * 64 + mi * 16 + l16) * 32 + quad * 8]);
#pragma unroll
    for (int ni = 0; ni < 6; ++ni)
      bf[ni] = *(const short8*)(&Bs[(wn * 96 + ni * 16 + l16) * 32 + quad * 8]);
#pragma unroll
    for (int mi = 0; mi < 4; ++mi)
#pragma unroll
      for (int ni = 0; ni < 6; ++ni)
        acc[mi][ni] = mfma_bf16(af[mi], bf[ni], acc[mi][ni]);

    // write A(kk+1) into the other set AFTER compute (loads have landed)
    if (pf) {
      *(uint4*)(&nset[oA0]) = pack8_bf16(a00, a01);
      *(uint4*)(&nset[oA1]) = pack8_bf16(a10, a11);
    }
    __syncthreads();  // (a) drains B prefetch + A writes (b) protects set[cur]
  }

  if (seg != 2) {
    const float* bias = (seg == 0) ? bq : bk;
    unsigned short* Out = (seg == 0) ? Qb : Kb;
    const float scale = (seg == 0) ? kQScale : 1.0f;
#pragma unroll
    for (int ni = 0; ni < 6; ++ni) {
      int n = nloc0 + wn * 96 + ni * 16 + l16;
      float bias_v = bias[n];
#pragma unroll
      for (int mi = 0; mi < 4; ++mi) {
#pragma unroll
        for (int r = 0; r < 4; ++r) {
          int m = bm + wm * 64 + mi * 16 + quad * 4 + r;
          Out[(size_t)m * Dm + n] = f32_to_bf16((acc[mi][ni][r] + bias_v) * scale);
        }
      }
    }
  } else {
    // V: two-pass LDS transpose, then coalesced 256B-row stores of V^T.
    const int bb = bm >> 11;       // batch
    const int s0 = bm & 2047;      // seq offset
    const int j = tid >> 4;        // 0..15
    const int cch = tid & 15;      // 16B chunk
#pragma unroll
    for (int p = 0; p < 2; ++p) {
      if (wn == p) {
#pragma unroll
        for (int ni = 0; ni < 6; ++ni) {
          int nl = ni * 16 + l16;  // row within 96
          float bias_v = bv[nloc0 + p * 96 + nl];
#pragma unroll
          for (int mi = 0; mi < 4; ++mi)
#pragma unroll
            for (int r = 0; r < 4; ++r)
              Sh[nl * 136 + wm * 64 + mi * 16 + quad * 4 + r] =
                  f32_to_bf16(acc[mi][ni][r] + bias_v);
        }
      }
      __syncthreads();
#pragma unroll
      for (int it = 0; it < 6; ++it) {
        int row = it * 16 + j;
        int nv = nloc0 + p * 96 + row;
        int h2 = nv >> 6, dcol = nv & 63;
        uint4 v = *(const uint4*)(&Sh[row * 136 + cch * 8]);
        *(uint4*)(&Vt[((size_t)((bb * Hn + h2) * 64 + dcol)) * Sn + s0 + cch * 8]) = v;
      }
      __syncthreads();
    }
  }
}

// ---------------- flash attention (mixed softmax + relu^2) ----------------
// R8 structure (94.9us): 256 thr / 4 waves, 32 q-rows/wave, lacc ones-MFMA
// denominator, unroll-2 kt loop, pointer-incremented prefetch, setprio(1)
// around MFMA clusters.
__global__ __launch_bounds__(256, 3) void k_attn(
    const unsigned short* __restrict__ Qb, const unsigned short* __restrict__ Kb,
    const unsigned short* __restrict__ Vt, const float* __restrict__ wmix,
    unsigned short* __restrict__ Ctx) {
  __shared__ unsigned short Ks[2][64 * 64];   // [buf][row(key)][dh] swizzled
  __shared__ unsigned short Vs[2][64 * 64];   // [buf][dh][key] swizzled

  const int tid = threadIdx.x;
  const int wave = tid >> 6, lane = tid & 63;
  const int quad = lane >> 4, l16 = lane & 15;
  const int l8 = l16 & 7;
  // XCD-aware swizzle: lin = qt*48 + s ; bh = (s&7)*6 + (s>>3)
  const int lin = blockIdx.x;
  const int qt = lin / 48;
  const int s = lin % 48;
  const int bh = (s & 7) * 6 + (s >> 3);
  const int b = bh / Hn, h = bh % Hn;

  const unsigned short* Qg = Qb + (size_t)(b * Sn + qt * 128) * Dm + h * 64;
  const unsigned short* Kg = Kb + (size_t)(b * Sn) * Dm + h * 64;
  const unsigned short* Vg = Vt + (size_t)bh * 64 * Sn;

  const int krr = lane >> 3, kcc = lane & 7;
  const int kchunk = kcc ^ krr;   // global 16B chunk fetched by this lane

  // ---- stage Q tile (128x64 = 16KB) across Ks[0]+Ks[1] as scratch ----
#pragma unroll
  for (int i = 0; i < 4; ++i) {
    int t = wave * 4 + i;  // 0..15 1KB blocks
    gload_lds16(Qg + (size_t)(t * 8 + krr) * Dm + kchunk * 8, &Ks[0][0] + t * 512);
  }
  __syncthreads();
  short8 qf[2][2];
#pragma unroll
  for (int mi = 0; mi < 2; ++mi)
#pragma unroll
    for (int ks = 0; ks < 2; ++ks)
      qf[mi][ks] = *(const short8*)(
          &Ks[wave >> 1][((wave & 1) * 32 + mi * 16 + l16) * 64 +
                         (((ks * 4 + quad) ^ l8) << 3)]);
  __syncthreads();  // protect Ks from kt0 staging until all qf reads done

  const f32x4 kZero = {0.f, 0.f, 0.f, 0.f};
  short8 ones;
#pragma unroll
  for (int i = 0; i < 8; ++i) ones[i] = (short)0x3F80;  // bf16(1.0)

  f32x4 acc_s[2][4], acc_r2[2][4], lacc[2];
#pragma unroll
  for (int i = 0; i < 2; ++i) {
#pragma unroll
    for (int j = 0; j < 4; ++j)
#pragma unroll
      for (int r = 0; r < 4; ++r) { acc_s[i][j][r] = 0.f; acc_r2[i][j][r] = 0.f; }
#pragma unroll
    for (int r = 0; r < 4; ++r) lacc[i][r] = 0.f;
  }

  // prefetch pointers, byte-stepped per kt (t0/t1 = this wave's two 1KB blocks)
  const unsigned short* kp0;
  const unsigned short* kp1;
  const unsigned short* vp0;
  const unsigned short* vp1;
  {
    int t0 = wave * 2 + 0, t1 = wave * 2 + 1;
    kp0 = Kg + (size_t)(64 + t0 * 8 + krr) * Dm + kchunk * 8;
    kp1 = Kg + (size_t)(64 + t1 * 8 + krr) * Dm + kchunk * 8;
    vp0 = Vg + (size_t)(t0 * 8 + krr) * Sn + 64 + kchunk * 8;
    vp1 = Vg + (size_t)(t1 * 8 + krr) * Sn + 64 + kchunk * 8;
  }

  // stage kt=0 into buf0
#pragma unroll
  for (int i = 0; i < 2; ++i) {
    int t = wave * 2 + i;  // 0..7
    gload_lds16(Kg + (size_t)(t * 8 + krr) * Dm + kchunk * 8, &Ks[0][t * 512]);
    gload_lds16(Vg + (size_t)(t * 8 + krr) * Sn + kchunk * 8, &Vs[0][t * 512]);
  }
  __syncthreads();  // buf0 ready

#pragma unroll 2
  for (int kt = 0; kt < 32; ++kt) {
    const int cur = kt & 1;
    // prefetch kt+1 into the other buffer; lands during compute below
    if (kt < 31) {
      const int nxt = cur ^ 1;
      const int t0 = wave * 2 + 0, t1 = wave * 2 + 1;
      gload_lds16(kp0, &Ks[nxt][t0 * 512]);
      gload_lds16(vp0, &Vs[nxt][t0 * 512]);
      gload_lds16(kp1, &Ks[nxt][t1 * 512]);
      gload_lds16(vp1, &Vs[nxt][t1 * 512]);
      kp0 += 64 * Dm; kp1 += 64 * Dm;
      vp0 += 64;      vp1 += 64;
    }

    // compute on buf[cur]: 64 keys as 2 chunks of 32
#pragma unroll
    for (int c = 0; c < 2; ++c) {
      short8 kf[2][2];
#pragma unroll
      for (int t2 = 0; t2 < 2; ++t2)
#pragma unroll
        for (int ks = 0; ks < 2; ++ks)
          kf[t2][ks] = *(const short8*)(
              &Ks[cur][(c * 32 + t2 * 16 + l16) * 64 + (((ks * 4 + quad) ^ l8) << 3)]);

      f32x4 sacc[2][2];
      __builtin_amdgcn_s_setprio(1);
#pragma unroll
      for (int mi = 0; mi < 2; ++mi)
#pragma unroll
        for (int t2 = 0; t2 < 2; ++t2)
          sacc[mi][t2] = mfma_bf16(kf[t2][1], qf[mi][1],
                                   mfma_bf16(kf[t2][0], qf[mi][0], kZero));
      __builtin_amdgcn_s_setprio(0);

      short8 vf[4];
#pragma unroll
      for (int nv = 0; nv < 4; ++nv)
        vf[nv] = *(const short8*)(
            &Vs[cur][(nv * 16 + l16) * 64 + (((c * 4 + quad) ^ l8) << 3)]);

#pragma unroll
      for (int mi = 0; mi < 2; ++mi) {
        f32x4 s0 = sacc[mi][0], s1 = sacc[mi][1];
        float p1a[4], p1b[4], p2a[4], p2b[4];
#pragma unroll
        for (int r = 0; r < 4; ++r) {
          p1a[r] = __builtin_amdgcn_exp2f(s0[r]);
          p1b[r] = __builtin_amdgcn_exp2f(s1[r]);
          float t0 = fmaxf(s0[r], 0.f), t1 = fmaxf(s1[r], 0.f);
          p2a[r] = t0 * t0;
          p2b[r] = t1 * t1;
        }
        short8 pf1 = transpose_to_bfrag(cvt_pk_bf16(p1a[0], p1a[1]),
                                        cvt_pk_bf16(p1a[2], p1a[3]),
                                        cvt_pk_bf16(p1b[0], p1b[1]),
                                        cvt_pk_bf16(p1b[2], p1b[3]));
        short8 pf2 = transpose_to_bfrag(cvt_pk_bf16(p2a[0], p2a[1]),
                                        cvt_pk_bf16(p2a[2], p2a[3]),
                                        cvt_pk_bf16(p2b[0], p2b[1]),
                                        cvt_pk_bf16(p2b[2], p2b[3]));
        __builtin_amdgcn_s_setprio(1);
#pragma unroll
        for (int nv = 0; nv < 4; ++nv) {
          acc_s[mi][nv] = mfma_bf16(vf[nv], pf1, acc_s[mi][nv]);
          acc_r2[mi][nv] = mfma_bf16(vf[nv], pf2, acc_r2[mi][nv]);
        }
        lacc[mi] = mfma_bf16(ones, pf1, lacc[mi]);  // D[*][q] = sum_k p1
        __builtin_amdgcn_s_setprio(0);
      }
    }
    __syncthreads();  // (a) drains prefetch (landed during compute)
                      // (b) protects buf[cur] before kt+1 restages it
  }

  float w0 = wmix[0], w1 = wmix[1];
  float e0 = __expf(w0), e1 = __expf(w1);
  float mix0 = e0 / (e0 + e1);
  float mix1 = (e1 / (e0 + e1)) * kR2Fix;  // undo (log2e)^2 in relu^2 branch

#pragma unroll
  for (int mi = 0; mi < 2; ++mi) {
    float a0 = mix0 / lacc[mi][0];
    int srow = qt * 128 + wave * 32 + mi * 16 + l16;
#pragma unroll
    for (int nv = 0; nv < 4; ++nv) {
      float v0 = fmaf(acc_s[mi][nv][0], a0, mix1 * acc_r2[mi][nv][0]);
      float v1 = fmaf(acc_s[mi][nv][1], a0, mix1 * acc_r2[mi][nv][1]);
      float v2 = fmaf(acc_s[mi][nv][2], a0, mix1 * acc_r2[mi][nv][2]);
      float v3 = fmaf(acc_s[mi][nv][3], a0, mix1 * acc_r2[mi][nv][3]);
      uint2 o;
      o.x = cvt_pk_bf16(v0, v1);
      o.y = cvt_pk_bf16(v2, v3);
      *(uint2*)(&Ctx[(size_t)(b * Sn + srow) * Dm + h * 64 + nv * 16 + quad * 4]) = o;
    }
  }
}

// ---------------- output projection GEMM (fp32 out) ----------------
// Double-buffered staging; unroll-2; incremented pointers; XCD-chunked
// swizzle (384 blocks, 384%8==0 -> bijective).
__global__ __launch_bounds__(256, 3) void k_gemm_out(
    const unsigned short* __restrict__ Abf, const unsigned short* __restrict__ W,
    const float* __restrict__ bias, float* __restrict__ out) {
  __shared__ unsigned short Sh2[2 * 8192];  // 2 sets of [As 4096 | Bs 4096]

  const int tid = threadIdx.x;
  const int wave = tid >> 6, lane = tid & 63;
  const int wm = wave >> 1, wn = wave & 1;
  const int quad = lane >> 4, l16 = lane & 15;
  const int lin = blockIdx.x;
  const int swz = (lin & 7) * 48 + (lin >> 3);
  const int bxi = swz % 6, byi = swz / 6;
  const int bm = byi * 128, bn = bxi * 128;

  const int sr = lane >> 2;
  const int sc = (lane & 3) * 8;
  const unsigned short* gA0 = Abf + (size_t)(bm + (wave * 2 + 0) * 16 + sr) * Dm + sc;
  const unsigned short* gA1 = Abf + (size_t)(bm + (wave * 2 + 1) * 16 + sr) * Dm + sc;
  const unsigned short* gB0 = W + (size_t)(bn + (wave * 2 + 0) * 16 + sr) * Dm + sc;
  const unsigned short* gB1 = W + (size_t)(bn + (wave * 2 + 1) * 16 + sr) * Dm + sc;
  const int oA0 = (wave * 2 + 0) * 512;
  const int oA1 = (wave * 2 + 1) * 512;
  const int oB0 = 4096 + (wave * 2 + 0) * 512;
  const int oB1 = 4096 + (wave * 2 + 1) * 512;

  f32x4 acc[4][4];
#pragma unroll
  for (int i = 0; i < 4; ++i)
#pragma unroll
    for (int j = 0; j < 4; ++j)
#pragma unroll
      for (int r = 0; r < 4; ++r) acc[i][j][r] = 0.f;

  // prologue: stage kk=0 into set 0
  gload_lds16(gA0, &Sh2[oA0]);
  gload_lds16(gA1, &Sh2[oA1]);
  gload_lds16(gB0, &Sh2[oB0]);
  gload_lds16(gB1, &Sh2[oB1]);
  __syncthreads();

  const unsigned short* pA0 = gA0 + 32;
  const unsigned short* pA1 = gA1 + 32;
  const unsigned short* pB0 = gB0 + 32;
  const unsigned short* pB1 = gB1 + 32;

  constexpr int NK = Dm / 32;  // 24
#pragma unroll 2
  for (int kk = 0; kk < NK; ++kk) {
    const int cur = kk & 1;
    if (kk + 1 < NK) {
      unsigned short* nset = &Sh2[(cur ^ 1) * 8192];
      gload_lds16(pA0, nset + oA0);
      gload_lds16(pA1, nset + oA1);
      gload_lds16(pB0, nset + oB0);
      gload_lds16(pB1, nset + oB1);
      pA0 += 32; pA1 += 32; pB0 += 32; pB1 += 32;
    }

    const unsigned short* As = &Sh2[cur * 8192];
    const unsigned short* Bs = As + 4096;
    short8 af[4], bf[4];
#pragma unroll
    for (int mi = 0; mi < 4; ++mi)
      af[mi] = *(const short8*)(&As[(wm * 64 + mi * 16 + l16) * 32 + quad * 8]);
#pragma unroll
    for (int ni = 0; ni < 4; ++ni)
      bf[ni] = *(const short8*)(&Bs[(wn * 64 + ni * 16 + l16) * 32 + quad * 8]);
#pragma unroll
    for (int mi = 0; mi < 4; ++mi)
#pragma unroll
      for (int ni = 0; ni < 4; ++ni)
        acc[mi][ni] = mfma_bf16(af[mi], bf[ni], acc[mi][ni]);
    __syncthreads();
  }

#pragma unroll
  for (int ni = 0; ni < 4; ++ni) {
    int n = bn + wn * 64 + ni * 16 + l16;
    float bias_v = bias[n];
#pragma unroll
    for (int mi = 0; mi < 4; ++mi) {
#pragma unroll
      for (int r = 0; r < 4; ++r) {
        int m = bm + wm * 64 + mi * 16 + quad * 4 + r;
        out[(size_t)m * Dm + n] = acc[mi][ni][r] + bias_v;
      }
    }
  }
}

extern "C" void kernel_launch(void* const* d_in, const int* in_sizes, int n_in,
                              void* d_out, int out_size, void* d_ws, size_t ws_size,
                              hipStream_t stream) {
  const float* hs = (const float*)d_in[0];
  const float* Wq = (const float*)d_in[1];
  const float* bq = (const float*)d_in[2];
  const float* Wk = (const float*)d_in[3];
  const float* bk = (const float*)d_in[4];
  const float* Wv = (const float*)d_in[5];
  const float* bv = (const float*)d_in[6];
  const float* Wo = (const float*)d_in[7];
  const float* bo = (const float*)d_in[8];
  const float* wmix = (const float*)d_in[9];

  unsigned short* hbf = (unsigned short*)d_ws;          // scratch (Ctx)
  unsigned short* wbf = hbf + (size_t)Mn * Dm;          // 4*768*768 ([Wq;Wk;Wv;Wo])
  unsigned short* Qb  = wbf + (size_t)4 * Dm * Dm;      // 8192*768
  unsigned short* Kb  = Qb + (size_t)Mn * Dm;           // 8192*768
  unsigned short* Vt  = Kb + (size_t)Mn * Dm;           // 48*64*2048
  unsigned short* Ctx = hbf;

  k_cast_w<<<dim3(2304), dim3(256), 0, stream>>>(Wq, Wk, Wv, Wo, wbf);
  k_gemm_qkv<<<dim3(768), dim3(256), 0, stream>>>(hs, wbf, bq, bk, bv, Qb, Kb, Vt);
  k_attn<<<dim3(768), dim3(256), 0, stream>>>(Qb, Kb, Vt, wmix, Ctx);
  k_gemm_out<<<dim3(384), dim3(256), 0, stream>>>(Ctx, wbf + (size_t)3 * Dm * Dm, bo,
                                                  (float*)d_out);
}

// Round 10
// 227.990 us; speedup vs baseline: 1.0194x; 1.0194x over previous
//
#include <hip/hip_runtime.h>

#define DEV __device__ __forceinline__

typedef __attribute__((ext_vector_type(8))) short short8;
typedef __attribute__((ext_vector_type(4))) float f32x4;
typedef __attribute__((ext_vector_type(2))) unsigned int u32x2;
typedef __attribute__((ext_vector_type(4))) unsigned int u32x4;

constexpr int Dm = 768;   // model dim
constexpr int Sn = 2048;  // seq len
constexpr int Bn = 4;     // batch
constexpr int Hn = 12;    // heads
constexpr int Mn = Bn * Sn;  // 8192 rows

// Q is pre-scaled by 0.125*log2(e) so scores come out as s*log2(e):
// p1 = exp2(sacc) = e^s ; p2 = relu(sacc)^2 = (log2e)^2 * relu(s)^2
constexpr float kQScale = 0.18033688011112043f;     // 0.125 * log2(e)
constexpr float kR2Fix  = 0.4804530139182014f;      // 1 / (log2(e))^2

// gfx950: pack two fp32 -> bf16x2 dword in ONE VALU op (RNE).
DEV unsigned cvt_pk_bf16(float lo, float hi) {
  unsigned d;
  asm("v_cvt_pk_bf16_f32 %0, %1, %2" : "=v"(d) : "v"(lo), "v"(hi));
  return d;
}

// single f32 -> bf16 in ONE VALU op (RNE; replaces 4-op manual rounding)
DEV unsigned short f32_to_bf16(float f) {
  return (unsigned short)cvt_pk_bf16(f, f);
}

DEV f32x4 mfma_bf16(short8 a, short8 b, f32x4 c) {
  return __builtin_amdgcn_mfma_f32_16x16x32_bf16(a, b, c, 0, 0, 0);
}

// async global->LDS, 16B per lane; LDS dest = wave-uniform base + lane*16
DEV void gload_lds16(const void* g, void* l) {
  __builtin_amdgcn_global_load_lds(
      (__attribute__((address_space(1))) const unsigned int*)g,
      (__attribute__((address_space(3))) unsigned int*)l, 16, 0, 0);
}

// Transform two 16x16 S^T C-layout tiles (packed as bf16 dwords) into one
// B-operand fragment for mfma_16x16x32 (K=32 keys spanning both tiles).
DEV short8 transpose_to_bfrag(unsigned xd0, unsigned xd1, unsigned yd0, unsigned yd1) {
  u32x2 a0 = __builtin_amdgcn_permlane32_swap(xd0, yd0, false, false);
  u32x2 b0 = __builtin_amdgcn_permlane16_swap(a0[0], a0[1], false, false);
  u32x2 a1 = __builtin_amdgcn_permlane32_swap(xd1, yd1, false, false);
  u32x2 b1 = __builtin_amdgcn_permlane16_swap(a1[0], a1[1], false, false);
  u32x4 f = {b0[0], b1[0], b0[1], b1[1]};
  return __builtin_bit_cast(short8, f);
}

// ---------------- merged cast kernel (one launch) ----------------
__global__ __launch_bounds__(256) void k_cast_all(
    const float* __restrict__ hs, const float* __restrict__ Wq,
    const float* __restrict__ Wk, const float* __restrict__ Wv,
    const float* __restrict__ Wo, unsigned short* __restrict__ hbf,
    unsigned short* __restrict__ wbf) {
  int bx = blockIdx.x;
  if (bx < 6144) {
    int i = bx * 256 + threadIdx.x;     // hidden: 6144*256 float4
    float4 v = ((const float4*)hs)[i];
    uint2 o;
    o.x = cvt_pk_bf16(v.x, v.y);
    o.y = cvt_pk_bf16(v.z, v.w);
    ((uint2*)hbf)[i] = o;
  } else {
    int i = (bx - 6144) * 256 + threadIdx.x;  // weights: 4*147456 float4
    int w = i / 147456;
    int off = i - w * 147456;
    const float* src = (w == 0) ? Wq : (w == 1) ? Wk : (w == 2) ? Wv : Wo;
    float4 v = ((const float4*)src)[off];
    uint2 o;
    o.x = cvt_pk_bf16(v.x, v.y);
    o.y = cvt_pk_bf16(v.z, v.w);
    ((uint2*)wbf)[w * 147456 + off] = o;
  }
}

// ---------------- merged QKV projection GEMM ----------------
// Double-buffered LDS staging; unroll-2 kk loop (compile-time buffer index);
// incremented staging pointers; XCD-chunked swizzle (768%8==0 bijective;
// each XCD gets 8 complete A-panels with all 12 N-readers co-located).
// NEW this round: 1-op cvt_pk bf16 converts in the epilogues, and the
// V-transpose epilogue packs r-pairs into ds_write_b32 (48 writes vs 96
// scalar b16) — V blocks are the kernel's straggler tail.
__global__ __launch_bounds__(256, 3) void k_gemm_qkv(
    const unsigned short* __restrict__ Abf, const unsigned short* __restrict__ wbf,
    const float* __restrict__ bq, const float* __restrict__ bk, const float* __restrict__ bv,
    unsigned short* __restrict__ Qb, unsigned short* __restrict__ Kb,
    unsigned short* __restrict__ Vt) {
  // union: 2 staging sets [As 128x32 | Bs 192x32] = 2*10240 shorts (40 KB)
  //        | V-transpose tile [96][136] = 13056 shorts (26 KB)
  __shared__ unsigned short Sh[2 * 10240];

  const int tid = threadIdx.x;
  const int wave = tid >> 6, lane = tid & 63;
  const int wm = wave >> 1, wn = wave & 1;
  const int quad = lane >> 4, l16 = lane & 15;
  // XCD-chunked swizzle: 768 blocks, 768%8==0 -> bijective.
  const int lin = blockIdx.x;
  const int swz = (lin & 7) * 96 + (lin >> 3);
  const int bxi = swz % 12;                   // N panel 0..11
  const int byi = swz / 12;                   // M panel 0..63
  const int bm = byi * 128, bn = bxi * 192;
  const int seg = bxi >> 2;                   // 0=Q 1=K 2=V
  const int nloc0 = (bxi & 3) * 192;          // column offset within 768

  const int sr = lane >> 2;
  const int sc = (lane & 3) * 8;
  const unsigned short* gA0 = Abf + (size_t)(bm + (wave * 2 + 0) * 16 + sr) * Dm + sc;
  const unsigned short* gA1 = Abf + (size_t)(bm + (wave * 2 + 1) * 16 + sr) * Dm + sc;
  const unsigned short* gB0 = wbf + (size_t)(bn + (wave * 3 + 0) * 16 + sr) * Dm + sc;
  const unsigned short* gB1 = wbf + (size_t)(bn + (wave * 3 + 1) * 16 + sr) * Dm + sc;
  const unsigned short* gB2 = wbf + (size_t)(bn + (wave * 3 + 2) * 16 + sr) * Dm + sc;
  // per-wave LDS staging offsets (within one set)
  const int oA0 = (wave * 2 + 0) * 512;
  const int oA1 = (wave * 2 + 1) * 512;
  const int oB0 = 4096 + (wave * 3 + 0) * 512;
  const int oB1 = 4096 + (wave * 3 + 1) * 512;
  const int oB2 = 4096 + (wave * 3 + 2) * 512;

  f32x4 acc[4][6];
#pragma unroll
  for (int i = 0; i < 4; ++i)
#pragma unroll
    for (int j = 0; j < 6; ++j)
#pragma unroll
      for (int r = 0; r < 4; ++r) acc[i][j][r] = 0.f;

  // prologue: stage kk=0 into set 0
  gload_lds16(gA0, &Sh[oA0]);
  gload_lds16(gA1, &Sh[oA1]);
  gload_lds16(gB0, &Sh[oB0]);
  gload_lds16(gB1, &Sh[oB1]);
  gload_lds16(gB2, &Sh[oB2]);
  __syncthreads();  // set 0 ready

  // pointers to the NEXT k-step to stage
  const unsigned short* pA0 = gA0 + 32;
  const unsigned short* pA1 = gA1 + 32;
  const unsigned short* pB0 = gB0 + 32;
  const unsigned short* pB1 = gB1 + 32;
  const unsigned short* pB2 = gB2 + 32;

  constexpr int NK = Dm / 32;  // 24
#pragma unroll 2
  for (int kk = 0; kk < NK; ++kk) {
    const int cur = kk & 1;
    // prefetch kk+1 into the other set; lands during compute below
    if (kk + 1 < NK) {
      unsigned short* nset = &Sh[(cur ^ 1) * 10240];
      gload_lds16(pA0, nset + oA0);
      gload_lds16(pA1, nset + oA1);
      gload_lds16(pB0, nset + oB0);
      gload_lds16(pB1, nset + oB1);
      gload_lds16(pB2, nset + oB2);
      pA0 += 32; pA1 += 32; pB0 += 32; pB1 += 32; pB2 += 32;
    }

    const unsigned short* As = &Sh[cur * 10240];
    const unsigned short* Bs = As + 4096;
    short8 af[4], bf[6];
#pragma unroll
    for (int mi = 0; mi < 4; ++mi)
      af[mi] = *(const short8*)(&As[(wm * 64 + mi * 16 + l16) * 32 + quad * 8]);
#pragma unroll
    for (int ni = 0; ni < 6; ++ni)
      bf[ni] = *(const short8*)(&Bs[(wn * 96 + ni * 16 + l16) * 32 + quad * 8]);
#pragma unroll
    for (int mi = 0; mi < 4; ++mi)
#pragma unroll
      for (int ni = 0; ni < 6; ++ni)
        acc[mi][ni] = mfma_bf16(af[mi], bf[ni], acc[mi][ni]);
    __syncthreads();  // (a) drains prefetch (b) protects set[cur] for reuse
  }

  if (seg != 2) {
    const float* bias = (seg == 0) ? bq : bk;
    unsigned short* Out = (seg == 0) ? Qb : Kb;
    const float scale = (seg == 0) ? kQScale : 1.0f;
#pragma unroll
    for (int ni = 0; ni < 6; ++ni) {
      int n = nloc0 + wn * 96 + ni * 16 + l16;
      float bias_v = bias[n];
#pragma unroll
      for (int mi = 0; mi < 4; ++mi) {
#pragma unroll
        for (int r = 0; r < 4; ++r) {
          int m = bm + wm * 64 + mi * 16 + quad * 4 + r;
          Out[(size_t)m * Dm + n] = f32_to_bf16((acc[mi][ni][r] + bias_v) * scale);
        }
      }
    }
  } else {
    // V: two-pass LDS transpose, then coalesced 256B-row stores of V^T.
    const int bb = bm >> 11;       // batch
    const int s0 = bm & 2047;      // seq offset
    const int j = tid >> 4;        // 0..15
    const int cch = tid & 15;      // 16B chunk
#pragma unroll
    for (int p = 0; p < 2; ++p) {
      if (wn == p) {
#pragma unroll
        for (int ni = 0; ni < 6; ++ni) {
          int nl = ni * 16 + l16;  // row within 96
          float bias_v = bv[nloc0 + p * 96 + nl];
#pragma unroll
          for (int mi = 0; mi < 4; ++mi)
#pragma unroll
            for (int r = 0; r < 4; r += 2) {
              // pack r,r+1 (adjacent columns) -> one aligned ds_write_b32
              unsigned pk = cvt_pk_bf16(acc[mi][ni][r] + bias_v,
                                        acc[mi][ni][r + 1] + bias_v);
              *(unsigned*)(&Sh[nl * 136 + wm * 64 + mi * 16 + quad * 4 + r]) = pk;
            }
        }
      }
      __syncthreads();
#pragma unroll
      for (int it = 0; it < 6; ++it) {
        int row = it * 16 + j;
        int nv = nloc0 + p * 96 + row;
        int h2 = nv >> 6, dcol = nv & 63;
        uint4 v = *(const uint4*)(&Sh[row * 136 + cch * 8]);
        *(uint4*)(&Vt[((size_t)((bb * Hn + h2) * 64 + dcol)) * Sn + s0 + cch * 8]) = v;
      }
      __syncthreads();
    }
  }
}

// ---------------- flash attention (mixed softmax + relu^2) ----------------
// R8 structure (94.9us, best): 256 thr / 4 waves, 32 q-rows/wave, lacc
// ones-MFMA denominator, unroll-2 kt loop, pointer-incremented prefetch,
// setprio(1) around MFMA clusters. Untouched this round.
__global__ __launch_bounds__(256, 3) void k_attn(
    const unsigned short* __restrict__ Qb, const unsigned short* __restrict__ Kb,
    const unsigned short* __restrict__ Vt, const float* __restrict__ wmix,
    unsigned short* __restrict__ Ctx) {
  __shared__ unsigned short Ks[2][64 * 64];   // [buf][row(key)][dh] swizzled
  __shared__ unsigned short Vs[2][64 * 64];   // [buf][dh][key] swizzled

  const int tid = threadIdx.x;
  const int wave = tid >> 6, lane = tid & 63;
  const int quad = lane >> 4, l16 = lane & 15;
  const int l8 = l16 & 7;
  // XCD-aware swizzle: lin = qt*48 + s ; bh = (s&7)*6 + (s>>3)
  const int lin = blockIdx.x;
  const int qt = lin / 48;
  const int s = lin % 48;
  const int bh = (s & 7) * 6 + (s >> 3);
  const int b = bh / Hn, h = bh % Hn;

  const unsigned short* Qg = Qb + (size_t)(b * Sn + qt * 128) * Dm + h * 64;
  const unsigned short* Kg = Kb + (size_t)(b * Sn) * Dm + h * 64;
  const unsigned short* Vg = Vt + (size_t)bh * 64 * Sn;

  const int krr = lane >> 3, kcc = lane & 7;
  const int kchunk = kcc ^ krr;   // global 16B chunk fetched by this lane

  // ---- stage Q tile (128x64 = 16KB) across Ks[0]+Ks[1] as scratch ----
#pragma unroll
  for (int i = 0; i < 4; ++i) {
    int t = wave * 4 + i;  // 0..15 1KB blocks
    gload_lds16(Qg + (size_t)(t * 8 + krr) * Dm + kchunk * 8, &Ks[0][0] + t * 512);
  }
  __syncthreads();
  short8 qf[2][2];
#pragma unroll
  for (int mi = 0; mi < 2; ++mi)
#pragma unroll
    for (int ks = 0; ks < 2; ++ks)
      qf[mi][ks] = *(const short8*)(
          &Ks[wave >> 1][((wave & 1) * 32 + mi * 16 + l16) * 64 +
                         (((ks * 4 + quad) ^ l8) << 3)]);
  __syncthreads();  // protect Ks from kt0 staging until all qf reads done

  const f32x4 kZero = {0.f, 0.f, 0.f, 0.f};
  short8 ones;
#pragma unroll
  for (int i = 0; i < 8; ++i) ones[i] = (short)0x3F80;  // bf16(1.0)

  f32x4 acc_s[2][4], acc_r2[2][4], lacc[2];
#pragma unroll
  for (int i = 0; i < 2; ++i) {
#pragma unroll
    for (int j = 0; j < 4; ++j)
#pragma unroll
      for (int r = 0; r < 4; ++r) { acc_s[i][j][r] = 0.f; acc_r2[i][j][r] = 0.f; }
#pragma unroll
    for (int r = 0; r < 4; ++r) lacc[i][r] = 0.f;
  }

  // prefetch pointers, byte-stepped per kt (t0/t1 = this wave's two 1KB blocks)
  const unsigned short* kp0;
  const unsigned short* kp1;
  const unsigned short* vp0;
  const unsigned short* vp1;
  {
    int t0 = wave * 2 + 0, t1 = wave * 2 + 1;
    kp0 = Kg + (size_t)(64 + t0 * 8 + krr) * Dm + kchunk * 8;
    kp1 = Kg + (size_t)(64 + t1 * 8 + krr) * Dm + kchunk * 8;
    vp0 = Vg + (size_t)(t0 * 8 + krr) * Sn + 64 + kchunk * 8;
    vp1 = Vg + (size_t)(t1 * 8 + krr) * Sn + 64 + kchunk * 8;
  }

  // stage kt=0 into buf0
#pragma unroll
  for (int i = 0; i < 2; ++i) {
    int t = wave * 2 + i;  // 0..7
    gload_lds16(Kg + (size_t)(t * 8 + krr) * Dm + kchunk * 8, &Ks[0][t * 512]);
    gload_lds16(Vg + (size_t)(t * 8 + krr) * Sn + kchunk * 8, &Vs[0][t * 512]);
  }
  __syncthreads();  // buf0 ready

#pragma unroll 2
  for (int kt = 0; kt < 32; ++kt) {
    const int cur = kt & 1;
    // prefetch kt+1 into the other buffer; lands during compute below
    if (kt < 31) {
      const int nxt = cur ^ 1;
      const int t0 = wave * 2 + 0, t1 = wave * 2 + 1;
      gload_lds16(kp0, &Ks[nxt][t0 * 512]);
      gload_lds16(vp0, &Vs[nxt][t0 * 512]);
      gload_lds16(kp1, &Ks[nxt][t1 * 512]);
      gload_lds16(vp1, &Vs[nxt][t1 * 512]);
      kp0 += 64 * Dm; kp1 += 64 * Dm;
      vp0 += 64;      vp1 += 64;
    }

    // compute on buf[cur]: 64 keys as 2 chunks of 32
#pragma unroll
    for (int c = 0; c < 2; ++c) {
      short8 kf[2][2];
#pragma unroll
      for (int t2 = 0; t2 < 2; ++t2)
#pragma unroll
        for (int ks = 0; ks < 2; ++ks)
          kf[t2][ks] = *(const short8*)(
              &Ks[cur][(c * 32 + t2 * 16 + l16) * 64 + (((ks * 4 + quad) ^ l8) << 3)]);

      f32x4 sacc[2][2];
      __builtin_amdgcn_s_setprio(1);
#pragma unroll
      for (int mi = 0; mi < 2; ++mi)
#pragma unroll
        for (int t2 = 0; t2 < 2; ++t2)
          sacc[mi][t2] = mfma_bf16(kf[t2][1], qf[mi][1],
                                   mfma_bf16(kf[t2][0], qf[mi][0], kZero));
      __builtin_amdgcn_s_setprio(0);

      short8 vf[4];
#pragma unroll
      for (int nv = 0; nv < 4; ++nv)
        vf[nv] = *(const short8*)(
            &Vs[cur][(nv * 16 + l16) * 64 + (((c * 4 + quad) ^ l8) << 3)]);

#pragma unroll
      for (int mi = 0; mi < 2; ++mi) {
        f32x4 s0 = sacc[mi][0], s1 = sacc[mi][1];
        float p1a[4], p1b[4], p2a[4], p2b[4];
#pragma unroll
        for (int r = 0; r < 4; ++r) {
          p1a[r] = __builtin_amdgcn_exp2f(s0[r]);
          p1b[r] = __builtin_amdgcn_exp2f(s1[r]);
          float t0 = fmaxf(s0[r], 0.f), t1 = fmaxf(s1[r], 0.f);
          p2a[r] = t0 * t0;
          p2b[r] = t1 * t1;
        }
        short8 pf1 = transpose_to_bfrag(cvt_pk_bf16(p1a[0], p1a[1]),
                                        cvt_pk_bf16(p1a[2], p1a[3]),
                                        cvt_pk_bf16(p1b[0], p1b[1]),
                                        cvt_pk_bf16(p1b[2], p1b[3]));
        short8 pf2 = transpose_to_bfrag(cvt_pk_bf16(p2a[0], p2a[1]),
                                        cvt_pk_bf16(p2a[2], p2a[3]),
                                        cvt_pk_bf16(p2b[0], p2b[1]),
                                        cvt_pk_bf16(p2b[2], p2b[3]));
        __builtin_amdgcn_s_setprio(1);
#pragma unroll
        for (int nv = 0; nv < 4; ++nv) {
          acc_s[mi][nv] = mfma_bf16(vf[nv], pf1, acc_s[mi][nv]);
          acc_r2[mi][nv] = mfma_bf16(vf[nv], pf2, acc_r2[mi][nv]);
        }
        lacc[mi] = mfma_bf16(ones, pf1, lacc[mi]);  // D[*][q] = sum_k p1
        __builtin_amdgcn_s_setprio(0);
      }
    }
    __syncthreads();  // (a) drains prefetch (landed during compute)
                      // (b) protects buf[cur] before kt+1 restages it
  }

  float w0 = wmix[0], w1 = wmix[1];
  float e0 = __expf(w0), e1 = __expf(w1);
  float mix0 = e0 / (e0 + e1);
  float mix1 = (e1 / (e0 + e1)) * kR2Fix;  // undo (log2e)^2 in relu^2 branch

#pragma unroll
  for (int mi = 0; mi < 2; ++mi) {
    float a0 = mix0 / lacc[mi][0];
    int srow = qt * 128 + wave * 32 + mi * 16 + l16;
#pragma unroll
    for (int nv = 0; nv < 4; ++nv) {
      float v0 = fmaf(acc_s[mi][nv][0], a0, mix1 * acc_r2[mi][nv][0]);
      float v1 = fmaf(acc_s[mi][nv][1], a0, mix1 * acc_r2[mi][nv][1]);
      float v2 = fmaf(acc_s[mi][nv][2], a0, mix1 * acc_r2[mi][nv][2]);
      float v3 = fmaf(acc_s[mi][nv][3], a0, mix1 * acc_r2[mi][nv][3]);
      uint2 o;
      o.x = cvt_pk_bf16(v0, v1);
      o.y = cvt_pk_bf16(v2, v3);
      *(uint2*)(&Ctx[(size_t)(b * Sn + srow) * Dm + h * 64 + nv * 16 + quad * 4]) = o;
    }
  }
}

// ---------------- output projection GEMM (fp32 out) ----------------
// Double-buffered staging; unroll-2; incremented pointers; XCD-chunked
// swizzle (384 blocks, 384%8==0 -> bijective).
__global__ __launch_bounds__(256, 3) void k_gemm_out(
    const unsigned short* __restrict__ Abf, const unsigned short* __restrict__ W,
    const float* __restrict__ bias, float* __restrict__ out) {
  __shared__ unsigned short Sh2[2 * 8192];  // 2 sets of [As 4096 | Bs 4096]

  const int tid = threadIdx.x;
  const int wave = tid >> 6, lane = tid & 63;
  const int wm = wave >> 1, wn = wave & 1;
  const int quad = lane >> 4, l16 = lane & 15;
  const int lin = blockIdx.x;
  const int swz = (lin & 7) * 48 + (lin >> 3);
  const int bxi = swz % 6, byi = swz / 6;
  const int bm = byi * 128, bn = bxi * 128;

  const int sr = lane >> 2;
  const int sc = (lane & 3) * 8;
  const unsigned short* gA0 = Abf + (size_t)(bm + (wave * 2 + 0) * 16 + sr) * Dm + sc;
  const unsigned short* gA1 = Abf + (size_t)(bm + (wave * 2 + 1) * 16 + sr) * Dm + sc;
  const unsigned short* gB0 = W + (size_t)(bn + (wave * 2 + 0) * 16 + sr) * Dm + sc;
  const unsigned short* gB1 = W + (size_t)(bn + (wave * 2 + 1) * 16 + sr) * Dm + sc;
  const int oA0 = (wave * 2 + 0) * 512;
  const int oA1 = (wave * 2 + 1) * 512;
  const int oB0 = 4096 + (wave * 2 + 0) * 512;
  const int oB1 = 4096 + (wave * 2 + 1) * 512;

  f32x4 acc[4][4];
#pragma unroll
  for (int i = 0; i < 4; ++i)
#pragma unroll
    for (int j = 0; j < 4; ++j)
#pragma unroll
      for (int r = 0; r < 4; ++r) acc[i][j][r] = 0.f;

  // prologue: stage kk=0 into set 0
  gload_lds16(gA0, &Sh2[oA0]);
  gload_lds16(gA1, &Sh2[oA1]);
  gload_lds16(gB0, &Sh2[oB0]);
  gload_lds16(gB1, &Sh2[oB1]);
  __syncthreads();

  const unsigned short* pA0 = gA0 + 32;
  const unsigned short* pA1 = gA1 + 32;
  const unsigned short* pB0 = gB0 + 32;
  const unsigned short* pB1 = gB1 + 32;

  constexpr int NK = Dm / 32;  // 24
#pragma unroll 2
  for (int kk = 0; kk < NK; ++kk) {
    const int cur = kk & 1;
    if (kk + 1 < NK) {
      unsigned short* nset = &Sh2[(cur ^ 1) * 8192];
      gload_lds16(pA0, nset + oA0);
      gload_lds16(pA1, nset + oA1);
      gload_lds16(pB0, nset + oB0);
      gload_lds16(pB1, nset + oB1);
      pA0 += 32; pA1 += 32; pB0 += 32; pB1 += 32;
    }

    const unsigned short* As = &Sh2[cur * 8192];
    const unsigned short* Bs = As + 4096;
    short8 af[4], bf[4];
#pragma unroll
    for (int mi = 0; mi < 4; ++mi)
      af[mi] = *(const short8*)(&As[(wm * 64 + mi * 16 + l16) * 32 + quad * 8]);
#pragma unroll
    for (int ni = 0; ni < 4; ++ni)
      bf[ni] = *(const short8*)(&Bs[(wn * 64 + ni * 16 + l16) * 32 + quad * 8]);
#pragma unroll
    for (int mi = 0; mi < 4; ++mi)
#pragma unroll
      for (int ni = 0; ni < 4; ++ni)
        acc[mi][ni] = mfma_bf16(af[mi], bf[ni], acc[mi][ni]);
    __syncthreads();
  }

#pragma unroll
  for (int ni = 0; ni < 4; ++ni) {
    int n = bn + wn * 64 + ni * 16 + l16;
    float bias_v = bias[n];
#pragma unroll
    for (int mi = 0; mi < 4; ++mi) {
#pragma unroll
      for (int r = 0; r < 4; ++r) {
        int m = bm + wm * 64 + mi * 16 + quad * 4 + r;
        out[(size_t)m * Dm + n] = acc[mi][ni][r] + bias_v;
      }
    }
  }
}

extern "C" void kernel_launch(void* const* d_in, const int* in_sizes, int n_in,
                              void* d_out, int out_size, void* d_ws, size_t ws_size,
                              hipStream_t stream) {
  const float* hs = (const float*)d_in[0];
  const float* Wq = (const float*)d_in[1];
  const float* bq = (const float*)d_in[2];
  const float* Wk = (const float*)d_in[3];
  const float* bk = (const float*)d_in[4];
  const float* Wv = (const float*)d_in[5];
  const float* bv = (const float*)d_in[6];
  const float* Wo = (const float*)d_in[7];
  const float* bo = (const float*)d_in[8];
  const float* wmix = (const float*)d_in[9];

  unsigned short* hbf = (unsigned short*)d_ws;          // 8192*768
  unsigned short* wbf = hbf + (size_t)Mn * Dm;          // 4*768*768 ([Wq;Wk;Wv;Wo])
  unsigned short* Qb  = wbf + (size_t)4 * Dm * Dm;      // 8192*768
  unsigned short* Kb  = Qb + (size_t)Mn * Dm;           // 8192*768
  unsigned short* Vt  = Kb + (size_t)Mn * Dm;           // 48*64*2048
  unsigned short* Ctx = hbf;                            // reuse (hbf dead after QKV)

  k_cast_all<<<dim3(8448), dim3(256), 0, stream>>>(hs, Wq, Wk, Wv, Wo, hbf, wbf);
  k_gemm_qkv<<<dim3(768), dim3(256), 0, stream>>>(hbf, wbf, bq, bk, bv, Qb, Kb, Vt);
  k_attn<<<dim3(768), dim3(256), 0, stream>>>(Qb, Kb, Vt, wmix, Ctx);
  k_gemm_out<<<dim3(384), dim3(256), 0, stream>>>(Ctx, wbf + (size_t)3 * Dm * Dm, bo,
                                                  (float*)d_out);
}